// Round 2
// baseline (496.903 us; speedup 1.0000x reference)
//
#include <hip/hip_runtime.h>
#include <hip/hip_cooperative_groups.h>
#include <math.h>

namespace cg = cooperative_groups;

#define H 256
#define L 50
#define V 50257
#define NBLK 512          // 2 blocks/CU on 256 CUs -- co-resident for coop launch
#define LOGIT_BLKS 448    // blocks 0..447 do logits; 448..511 do gru step 2
#define LOGIT_WAVES (LOGIT_BLKS * 4)
#define ROWS_PER_WAVE 29  // ceil(V / LOGIT_WAVES)

__device__ __forceinline__ float dot4(float4 a, float4 b) {
    return a.x * b.x + a.y * b.y + a.z * b.z + a.w * b.w;
}

__device__ __forceinline__ float wave_reduce_sum(float v) {
#pragma unroll
    for (int m = 32; m >= 1; m >>= 1) v += __shfl_xor(v, m, 64);
    return v;
}

__device__ __forceinline__ float wave_reduce_max(float v) {
#pragma unroll
    for (int m = 32; m >= 1; m >>= 1) v = fmaxf(v, __shfl_xor(v, m, 64));
    return v;
}

__device__ __forceinline__ float sigmoidf(float x) { return 1.0f / (1.0f + __expf(-x)); }

// One GRU cell output element j, computed by one wave.
// xv/hv are this lane's float4 slices of x and h; hj is h[j].
__device__ __forceinline__ void gru_wave(
    int j, int lane, float4 xv, float4 hv, float hj,
    const float* __restrict__ w_ih, const float* __restrict__ w_hh,
    const float* __restrict__ b_ih, const float* __restrict__ b_hh,
    float* __restrict__ outp)
{
    float gi[3], gh[3];
#pragma unroll
    for (int k = 0; k < 3; ++k) {
        int row = k * H + j;
        const float4* wi4 = (const float4*)(w_ih + (size_t)row * H);
        const float4* wh4 = (const float4*)(w_hh + (size_t)row * H);
        gi[k] = wave_reduce_sum(dot4(wi4[lane], xv)) + b_ih[row];
        gh[k] = wave_reduce_sum(dot4(wh4[lane], hv)) + b_hh[row];
    }
    if (lane == 0) {
        float r = sigmoidf(gi[0] + gh[0]);
        float z = sigmoidf(gi[1] + gh[1]);
        float n = tanhf(gi[2] + r * gh[2]);
        outp[j] = (1.f - z) * n + z * hj;
    }
}

__global__ __launch_bounds__(256, 2) void fused_decoder(
    const int* __restrict__ token, const float* __restrict__ hidden,
    const float* __restrict__ enc, const float* __restrict__ emb,
    const float* __restrict__ attn_W, const float* __restrict__ attn_b,
    const float* __restrict__ comb_W, const float* __restrict__ comb_b,
    const float* __restrict__ w_ih_f, const float* __restrict__ w_hh_f,
    const float* __restrict__ b_ih_f, const float* __restrict__ b_hh_f,
    const float* __restrict__ w_ih_b, const float* __restrict__ w_hh_b,
    const float* __restrict__ b_ih_b, const float* __restrict__ b_hh_b,
    const float* __restrict__ w_ih_g, const float* __restrict__ w_hh_g,
    const float* __restrict__ b_ih_g, const float* __restrict__ b_hh_g,
    const float* __restrict__ out_W, const float* __restrict__ out_b,
    float* __restrict__ out, float* __restrict__ ws)
{
    cg::grid_group grid = cg::this_grid();

    __shared__ float s_vec[2 * H];
    __shared__ float s_scores[L];
    __shared__ float s_aw[L];
    __shared__ float s_m[4], s_s[4];
    __shared__ float s_bcast;

    const int b = blockIdx.x, t = threadIdx.x;
    const int wid = t >> 6, lane = t & 63;

    float* ws_cat = ws;          // 512
    float* ws_x   = ws + 512;    // 256
    float* ws_hf  = ws + 768;    // 256
    float* ws_hb  = ws + 1024;   // 256
    float* ws_h1  = ws + 1280;   // 256
    float* ws_m   = ws + 1536;   // 512 per-block running max
    float* ws_s   = ws + 2048;   // 512 per-block running sum

    // ---------------- Stage A: attention (block 0 only) ----------------
    if (b == 0) {
        int tok = token[0];
        s_vec[t] = emb[(size_t)tok * H + t];
        s_vec[H + t] = hidden[t];
        __syncthreads();

        for (int l = wid; l < L; l += 4) {
            float acc = 0.f;
#pragma unroll
            for (int c = 0; c < 8; ++c)
                acc += attn_W[l * 2 * H + c * 64 + lane] * s_vec[c * 64 + lane];
            acc = wave_reduce_sum(acc);
            if (lane == 0) s_scores[l] = fmaxf(acc + attn_b[l], 0.f);  // relu
        }
        __syncthreads();

        if (t < 64) {  // softmax over 50 in wave 0
            float v = (t < L) ? s_scores[t] : -INFINITY;
            float m = wave_reduce_max(v);
            float e = (t < L) ? __expf(v - m) : 0.f;
            float s = wave_reduce_sum(e);
            float aw = e / s;
            if (t < L) { s_aw[t] = aw; out[V + H + t] = aw; }  // third output
        }
        __syncthreads();

        float acc = 0.f;
        for (int l = 0; l < L; ++l) acc += s_aw[l] * enc[l * H + t];
        ws_cat[t] = s_vec[t];
        ws_cat[H + t] = acc;
    }
    grid.sync();

    // ---------------- Stage B: x = relu(comb_W @ cat + b) (blocks 0..63) ----
    if (b < 64) {
        int row = b * 4 + wid;
        const float4* W4 = (const float4*)(comb_W + (size_t)row * 2 * H);
        const float4* c4 = (const float4*)ws_cat;
        float acc = dot4(W4[lane], c4[lane]) + dot4(W4[lane + 64], c4[lane + 64]);
        acc = wave_reduce_sum(acc);
        if (lane == 0) ws_x[row] = fmaxf(acc + comb_b[row], 0.f);
    }
    grid.sync();

    // ---------------- Stage C: bidirectional GRU (blocks 0..127) -----------
    if (b < 128) {
        int g = b * 4 + wid;  // 0..511
        int dir = g >> 8;
        int j = g & 255;
        const float4* x4 = (const float4*)ws_x;
        const float4* h4 = (const float4*)hidden;
        gru_wave(j, lane, x4[lane], h4[lane], hidden[j],
                 dir ? w_ih_b : w_ih_f, dir ? w_hh_b : w_hh_f,
                 dir ? b_ih_b : b_ih_f, dir ? b_hh_b : b_hh_f,
                 dir ? ws_hb : ws_hf);
    }
    grid.sync();

    // ---------------- Stage D: h1 = gru(hf, mean(hf,hb)) (blocks 0..63) ----
    if (b < 64) {
        int j = b * 4 + wid;
        const float4* x4 = (const float4*)ws_hf;
        const float4* a4 = (const float4*)ws_hf;
        const float4* b4 = (const float4*)ws_hb;
        float4 av = a4[lane], bv = b4[lane];
        float4 hv = make_float4(0.5f * (av.x + bv.x), 0.5f * (av.y + bv.y),
                                0.5f * (av.z + bv.z), 0.5f * (av.w + bv.w));
        float hj = 0.5f * (ws_hf[j] + ws_hb[j]);
        gru_wave(j, lane, x4[lane], hv, hj,
                 w_ih_g, w_hh_g, b_ih_g, b_hh_g, ws_h1);
    }
    grid.sync();

    // ---------------- Stage E: logits (blocks 0..447) || gru2 (448..511) ---
    if (b >= LOGIT_BLKS) {
        // h2 = gru(hb, h1): 64 blocks, wave per j. Weights L2-warm from stage D.
        int j = (b - LOGIT_BLKS) * 4 + wid;
        const float4* x4 = (const float4*)ws_hb;
        const float4* h4 = (const float4*)ws_h1;
        gru_wave(j, lane, x4[lane], h4[lane], ws_h1[j],
                 w_ih_g, w_hh_g, b_ih_g, b_hh_g, out + V);
        if (t == 0) { ws_m[b] = -INFINITY; ws_s[b] = 0.f; }
    } else {
        const int wave = b * 4 + wid;
        const float4* h4 = (const float4*)ws_h1;
        float4 hv = h4[lane];
        int start = wave * ROWS_PER_WAVE;
        int end = min(start + ROWS_PER_WAVE, V);
        float m = -INFINITY, s = 0.f;  // uniform across lanes (reduce is butterfly)
        for (int v = start; v < end; v += 2) {
            const float4* W0 = (const float4*)(out_W + (size_t)v * H);
            float4 a0 = W0[lane];
            bool has2 = (v + 1 < end);
            float4 a1 = has2 ? ((const float4*)(out_W + (size_t)(v + 1) * H))[lane]
                             : make_float4(0.f, 0.f, 0.f, 0.f);
            float x0 = wave_reduce_sum(dot4(a0, hv)) + out_b[v];
            float x1 = wave_reduce_sum(dot4(a1, hv));
            if (lane == 0) out[v] = x0;
            float mn = fmaxf(m, x0);
            s = s * __expf(m - mn) + __expf(x0 - mn);
            m = mn;
            if (has2) {
                x1 += out_b[v + 1];
                if (lane == 0) out[v + 1] = x1;
                mn = fmaxf(m, x1);
                s = s * __expf(m - mn) + __expf(x1 - mn);
                m = mn;
            }
        }
        if (lane == 0) { s_m[wid] = m; s_s[wid] = s; }
        __syncthreads();
        if (t == 0) {
            float M = s_m[0], S = s_s[0];
#pragma unroll
            for (int k = 1; k < 4; ++k) {
                float mk = s_m[k], sk = s_s[k];
                float mn = fmaxf(M, mk);
                // guard: empty waves carry (-inf, 0)
                S = (M > -INFINITY ? S * __expf(M - mn) : 0.f) +
                    (mk > -INFINITY ? sk * __expf(mk - mn) : 0.f);
                M = mn;
            }
            ws_m[b] = M; ws_s[b] = S;
        }
    }
    grid.sync();

    // ---------------- Stage F: lse + subtract (all blocks) ------------------
    {
        // fold 512 (m,s) pairs: thread t takes slots t and t+256
        float m1 = ws_m[t], s1 = ws_s[t];           // slot t<256: always real
        float m2 = ws_m[t + 256], s2 = ws_s[t + 256];
        float M = fmaxf(m1, m2);
        float s = s1 * __expf(m1 - M) + (m2 > -INFINITY ? s2 * __expf(m2 - M) : 0.f);
        float m = M;
#pragma unroll
        for (int d = 32; d >= 1; d >>= 1) {
            float om = __shfl_xor(m, d, 64);
            float os = __shfl_xor(s, d, 64);
            float mn = fmaxf(m, om);
            s = s * __expf(m - mn) + os * __expf(om - mn);
            m = mn;
        }
        if (lane == 0) { s_m[wid] = m; s_s[wid] = s; }
        __syncthreads();
        if (t == 0) {
            float M2 = s_m[0], S2 = s_s[0];
#pragma unroll
            for (int k = 1; k < 4; ++k) {
                float mk = s_m[k], sk = s_s[k];
                float mn = fmaxf(M2, mk);
                S2 = S2 * __expf(M2 - mn) + sk * __expf(mk - mn);
                M2 = mn;
            }
            s_bcast = M2 + logf(S2);
        }
        __syncthreads();
        float lse = s_bcast;
        int i = b * 256 + t;           // 131072 threads cover V
        if (i < V) out[i] -= lse;
    }
}

extern "C" void kernel_launch(void* const* d_in, const int* in_sizes, int n_in,
                              void* d_out, int out_size, void* d_ws, size_t ws_size,
                              hipStream_t stream)
{
    const int*   token  = (const int*)d_in[0];
    const float* hidden = (const float*)d_in[1];
    const float* enc    = (const float*)d_in[2];
    const float* emb    = (const float*)d_in[3];
    const float* attn_W = (const float*)d_in[4];
    const float* attn_b = (const float*)d_in[5];
    const float* comb_W = (const float*)d_in[6];
    const float* comb_b = (const float*)d_in[7];
    const float* w_ih_f = (const float*)d_in[8];
    const float* w_hh_f = (const float*)d_in[9];
    const float* b_ih_f = (const float*)d_in[10];
    const float* b_hh_f = (const float*)d_in[11];
    const float* w_ih_b = (const float*)d_in[12];
    const float* w_hh_b = (const float*)d_in[13];
    const float* b_ih_b = (const float*)d_in[14];
    const float* b_hh_b = (const float*)d_in[15];
    const float* w_ih_g = (const float*)d_in[16];
    const float* w_hh_g = (const float*)d_in[17];
    const float* b_ih_g = (const float*)d_in[18];
    const float* b_hh_g = (const float*)d_in[19];
    const float* out_W  = (const float*)d_in[20];
    const float* out_b  = (const float*)d_in[21];
    float* out = (float*)d_out;
    float* ws  = (float*)d_ws;

    void* args[] = {
        (void*)&token, (void*)&hidden, (void*)&enc, (void*)&emb,
        (void*)&attn_W, (void*)&attn_b, (void*)&comb_W, (void*)&comb_b,
        (void*)&w_ih_f, (void*)&w_hh_f, (void*)&b_ih_f, (void*)&b_hh_f,
        (void*)&w_ih_b, (void*)&w_hh_b, (void*)&b_ih_b, (void*)&b_hh_b,
        (void*)&w_ih_g, (void*)&w_hh_g, (void*)&b_ih_g, (void*)&b_hh_g,
        (void*)&out_W, (void*)&out_b, (void*)&out, (void*)&ws,
    };
    hipLaunchCooperativeKernel((const void*)fused_decoder,
                               dim3(NBLK), dim3(256), args, 0, stream);
}

// Round 3
// 383.144 us; speedup vs baseline: 1.2969x; 1.2969x over previous
//
#include <hip/hip_runtime.h>
#include <math.h>

#define H 256
#define L 50
#define V 50257
#define NBLK 512          // 2 blocks/CU on 256 CUs, co-resident (coop launch)
#define LOGIT_BLKS 448    // blocks 0..447 logits; 448..511 gru step 2
#define ROWS_PER_WAVE 29  // 448*4 waves * 29 = 51968 >= V
#define MAGIC 0x13572468

__device__ __forceinline__ float dot4(float4 a, float4 b) {
    return a.x * b.x + a.y * b.y + a.z * b.z + a.w * b.w;
}

__device__ __forceinline__ float wave_reduce_sum(float v) {
#pragma unroll
    for (int m = 32; m >= 1; m >>= 1) v += __shfl_xor(v, m, 64);
    return v;
}

__device__ __forceinline__ float wave_reduce_max(float v) {
#pragma unroll
    for (int m = 32; m >= 1; m >>= 1) v = fmaxf(v, __shfl_xor(v, m, 64));
    return v;
}

__device__ __forceinline__ float sigmoidf(float x) { return 1.0f / (1.0f + __expf(-x)); }

// online-softmax state helpers (NaN-safe for empty (-inf,0) states)
__device__ __forceinline__ void ms_push(float& m, float& s, float x) {
    float mn = fmaxf(m, x);
    s = s * __expf(m - mn) + __expf(x - mn);
    m = mn;
}
__device__ __forceinline__ void ms_merge(float& m, float& s, float om, float os) {
    float M = fmaxf(m, om);
    float a = (m == -INFINITY) ? 0.f : s * __expf(m - M);
    float c = (om == -INFINITY) ? 0.f : os * __expf(om - M);
    m = M; s = a + c;
}

// Fast single-use grid barrier. cnt must be 0 at first use (init gate
// guarantees this despite 0xAA ws poison). Writers release-fence (wbl2)
// BEFORE arriving; everyone acquire-fences (inv) after the count is full,
// so all dirty lines are at the coherent point before any inv happens.
__device__ __forceinline__ void gbar(int* cnt, bool writer) {
    __syncthreads();
    if (threadIdx.x == 0) {
        if (writer) __builtin_amdgcn_fence(__ATOMIC_RELEASE, "agent");
        __hip_atomic_fetch_add(cnt, 1, __ATOMIC_RELAXED, __HIP_MEMORY_SCOPE_AGENT);
        while (__hip_atomic_load(cnt, __ATOMIC_RELAXED, __HIP_MEMORY_SCOPE_AGENT) < NBLK)
            __builtin_amdgcn_s_sleep(1);
        __builtin_amdgcn_fence(__ATOMIC_ACQUIRE, "agent");
    }
    __syncthreads();
}

// One GRU cell output element j, computed by one wave.
__device__ __forceinline__ void gru_wave(
    int j, int lane, float4 xv, float4 hv, float hj,
    const float* __restrict__ w_ih, const float* __restrict__ w_hh,
    const float* __restrict__ b_ih, const float* __restrict__ b_hh,
    float* __restrict__ outp)
{
    float gi[3], gh[3];
#pragma unroll
    for (int k = 0; k < 3; ++k) {
        int row = k * H + j;
        const float4* wi4 = (const float4*)(w_ih + (size_t)row * H);
        const float4* wh4 = (const float4*)(w_hh + (size_t)row * H);
        gi[k] = wave_reduce_sum(dot4(wi4[lane], xv)) + b_ih[row];
        gh[k] = wave_reduce_sum(dot4(wh4[lane], hv)) + b_hh[row];
    }
    if (lane == 0) {
        float r = sigmoidf(gi[0] + gh[0]);
        float z = sigmoidf(gi[1] + gh[1]);
        float n = tanhf(gi[2] + r * gh[2]);
        outp[j] = (1.f - z) * n + z * hj;
    }
}

__global__ __launch_bounds__(256, 2) void fused_decoder(
    const int* __restrict__ token, const float* __restrict__ hidden,
    const float* __restrict__ enc, const float* __restrict__ emb,
    const float* __restrict__ attn_W, const float* __restrict__ attn_b,
    const float* __restrict__ comb_W, const float* __restrict__ comb_b,
    const float* __restrict__ w_ih_f, const float* __restrict__ w_hh_f,
    const float* __restrict__ b_ih_f, const float* __restrict__ b_hh_f,
    const float* __restrict__ w_ih_b, const float* __restrict__ w_hh_b,
    const float* __restrict__ b_ih_b, const float* __restrict__ b_hh_b,
    const float* __restrict__ w_ih_g, const float* __restrict__ w_hh_g,
    const float* __restrict__ b_ih_g, const float* __restrict__ b_hh_g,
    const float* __restrict__ out_W, const float* __restrict__ out_b,
    float* __restrict__ out, float* __restrict__ ws)
{
    __shared__ __align__(16) float s_vec[2 * H];   // [e | h0] -> [e | applied]
    __shared__ float s_scores[L];
    __shared__ float s_aw[L];
    __shared__ float s_m4[4], s_s4[4];
    __shared__ float s_bcast;
    __shared__ float s_logit[4][ROWS_PER_WAVE];    // per-wave logits stash

    const int b = blockIdx.x, t = threadIdx.x;
    const int wid = t >> 6, lane = t & 63;

    float* ws_x  = ws + 512;     // 256
    float* ws_hf = ws + 768;     // 256
    float* ws_hb = ws + 1024;    // 256
    float* ws_h1 = ws + 1280;    // 256
    float* ws_m  = ws + 1536;    // 512 per-block partial max
    float* ws_s  = ws + 2048;    // 512 per-block partial sum
    int*   ctrl  = (int*)(ws + 2560);  // cnt[k] at ctrl[k*16], gate at ctrl[64]
    float* sink  = ws + 2700;    // 2048 floats of prefetch sink

    if (b == 0) {
        // ---- init barrier counters + partial slots, open the gate ----
        if (t < 4)
            __hip_atomic_store(&ctrl[t * 16], 0, __ATOMIC_RELAXED, __HIP_MEMORY_SCOPE_AGENT);
        ws_m[t] = -INFINITY; ws_m[t + 256] = -INFINITY;
        ws_s[t] = 0.f;       ws_s[t + 256] = 0.f;
        __syncthreads();
        if (t == 0) {
            __builtin_amdgcn_fence(__ATOMIC_RELEASE, "agent");
            __hip_atomic_store(&ctrl[64], MAGIC, __ATOMIC_RELAXED, __HIP_MEMORY_SCOPE_AGENT);
        }

        // ---- Stage A: attention (hidden under other blocks' prefetch) ----
        int tok = token[0];
        s_vec[t] = emb[(size_t)tok * H + t];
        s_vec[H + t] = hidden[t];
        __syncthreads();
        for (int l = wid; l < L; l += 4) {
            float acc = 0.f;
#pragma unroll
            for (int c = 0; c < 8; ++c)
                acc += attn_W[l * 2 * H + c * 64 + lane] * s_vec[c * 64 + lane];
            acc = wave_reduce_sum(acc);
            if (lane == 0) s_scores[l] = fmaxf(acc + attn_b[l], 0.f);  // relu
        }
        __syncthreads();
        if (t < 64) {  // softmax over 50 in wave 0
            float v = (t < L) ? s_scores[t] : -INFINITY;
            float mx = wave_reduce_max(v);
            float e = (t < L) ? __expf(v - mx) : 0.f;
            float ssum = wave_reduce_sum(e);
            if (t < L) { float aw = e / ssum; s_aw[t] = aw; out[V + H + t] = aw; }
        }
        __syncthreads();
        float app = 0.f;
        for (int l = 0; l < L; ++l) app += s_aw[l] * enc[l * H + t];
        s_vec[H + t] = app;   // cat = [e | applied], LDS only
        __syncthreads();

        // ---- Stage B: x = relu(comb_W @ cat + b), 4 waves x 64 rows ----
        const float4* c4 = (const float4*)s_vec;
        for (int row = wid; row < H; row += 4) {
            const float4* W4 = (const float4*)(comb_W + (size_t)row * 2 * H);
            float acc = dot4(W4[lane], c4[lane]) + dot4(W4[lane + 64], c4[lane + 64]);
            acc = wave_reduce_sum(acc);
            if (lane == 0) ws_x[row] = fmaxf(acc + comb_b[row], 0.f);
        }
    } else {
        // ---- prefetch out_W into L3 (overlaps block 0's stages A+B) ----
        const float4* w4 = (const float4*)out_W;
        const int total4 = V * H / 4;                 // 3,216,448
        const int per = (total4 + NBLK - 2) / (NBLK - 1);
        int beg = (b - 1) * per;
        int fin = min(total4, b * per);
        float4 acc = make_float4(0.f, 0.f, 0.f, 0.f);
        for (int i = beg + t; i < fin; i += 256) {
            float4 q = w4[i];
            acc.x += q.x; acc.y += q.y; acc.z += q.z; acc.w += q.w;
        }
        float a = wave_reduce_sum(acc.x + acc.y + acc.z + acc.w);
        if (lane == 0) sink[b * 4 + wid] = a;  // DCE sink (scratch, never read)

        // ---- gate: wait until block 0 has zeroed the barrier counters ----
        __syncthreads();
        if (t == 0) {
            while (__hip_atomic_load(&ctrl[64], __ATOMIC_RELAXED, __HIP_MEMORY_SCOPE_AGENT) != MAGIC)
                __builtin_amdgcn_s_sleep(1);
            __builtin_amdgcn_fence(__ATOMIC_ACQUIRE, "agent");
        }
        __syncthreads();
    }

    gbar(&ctrl[0], b == 0);               // x ready

    // ---- Stage C: bidirectional GRU (blocks 0..127) ----
    if (b < 128) {
        int g = b * 4 + wid;  // (dir, j)
        int dir = g >> 8;
        int j = g & 255;
        gru_wave(j, lane, ((const float4*)ws_x)[lane], ((const float4*)hidden)[lane],
                 hidden[j],
                 dir ? w_ih_b : w_ih_f, dir ? w_hh_b : w_hh_f,
                 dir ? b_ih_b : b_ih_f, dir ? b_hh_b : b_hh_f,
                 dir ? ws_hb : ws_hf);
    }
    gbar(&ctrl[16], b < 128);             // hf, hb ready

    // ---- Stage D: h1 = gru(hf, mean(hf,hb)) (blocks 0..63) ----
    if (b < 64) {
        int j = b * 4 + wid;
        float4 av = ((const float4*)ws_hf)[lane];
        float4 bv = ((const float4*)ws_hb)[lane];
        float4 hv = make_float4(0.5f * (av.x + bv.x), 0.5f * (av.y + bv.y),
                                0.5f * (av.z + bv.z), 0.5f * (av.w + bv.w));
        float hj = 0.5f * (ws_hf[j] + ws_hb[j]);
        gru_wave(j, lane, av, hv, hj, w_ih_g, w_hh_g, b_ih_g, b_hh_g, ws_h1);
    }
    gbar(&ctrl[32], b < 64);              // h1 ready

    // ---- Stage E: logits (0..447) || h2 = gru(hb, h1) (448..511) ----
    if (b < LOGIT_BLKS) {
        const int wave = b * 4 + wid;
        float4 hv = ((const float4*)ws_h1)[lane];
        int start = wave * ROWS_PER_WAVE;
        int end = min(start + ROWS_PER_WAVE, V);
        float m = -INFINITY, s = 0.f;
        int k = 0;
        for (int v = start; v < end; v += 2, k += 2) {
            const float4* W0 = (const float4*)(out_W + (size_t)v * H);
            float4 a0 = W0[lane];
            bool has2 = (v + 1 < end);
            float4 a1 = has2 ? ((const float4*)(out_W + (size_t)(v + 1) * H))[lane]
                             : make_float4(0.f, 0.f, 0.f, 0.f);
            float x0 = wave_reduce_sum(dot4(a0, hv)) + out_b[v];
            float x1 = wave_reduce_sum(dot4(a1, hv));
            if (lane == 0) s_logit[wid][k] = x0;
            ms_push(m, s, x0);
            if (has2) {
                x1 += out_b[v + 1];
                if (lane == 0) s_logit[wid][k + 1] = x1;
                ms_push(m, s, x1);
            }
        }
        if (lane == 0) { s_m4[wid] = m; s_s4[wid] = s; }
        __syncthreads();
        if (t == 0) {
            float M = s_m4[0], S = s_s4[0];
#pragma unroll
            for (int q = 1; q < 4; ++q) ms_merge(M, S, s_m4[q], s_s4[q]);
            ws_m[b] = M; ws_s[b] = S;     // plain stores; released at bar3
        }
    } else {
        int j = (b - LOGIT_BLKS) * 4 + wid;
        gru_wave(j, lane, ((const float4*)ws_hb)[lane], ((const float4*)ws_h1)[lane],
                 ws_h1[j], w_ih_g, w_hh_g, b_ih_g, b_hh_g, out + V);
        // partial slots for these blocks stay at the (-inf, 0) init
    }
    gbar(&ctrl[48], b < LOGIT_BLKS);      // partials ready

    // ---- Stage F: fold 512 partials -> lse; subtract own rows from LDS ----
    if (b < LOGIT_BLKS) {
        float m = ws_m[t], s = ws_s[t];
        ms_merge(m, s, ws_m[t + 256], ws_s[t + 256]);
#pragma unroll
        for (int d = 32; d >= 1; d >>= 1) {
            float om = __shfl_xor(m, d, 64);
            float os = __shfl_xor(s, d, 64);
            ms_merge(m, s, om, os);
        }
        if (lane == 0) { s_m4[wid] = m; s_s4[wid] = s; }
        __syncthreads();
        if (t == 0) {
            float M = s_m4[0], S = s_s4[0];
#pragma unroll
            for (int q = 1; q < 4; ++q) ms_merge(M, S, s_m4[q], s_s4[q]);
            s_bcast = M + logf(S);
        }
        __syncthreads();
        float lse = s_bcast;
        const int wave = b * 4 + wid;
        int start = wave * ROWS_PER_WAVE;
        int rcount = min(ROWS_PER_WAVE, max(0, V - start));
        if (lane < rcount) out[start + lane] = s_logit[wid][lane] - lse;
    }
}

extern "C" void kernel_launch(void* const* d_in, const int* in_sizes, int n_in,
                              void* d_out, int out_size, void* d_ws, size_t ws_size,
                              hipStream_t stream)
{
    const int*   token  = (const int*)d_in[0];
    const float* hidden = (const float*)d_in[1];
    const float* enc    = (const float*)d_in[2];
    const float* emb    = (const float*)d_in[3];
    const float* attn_W = (const float*)d_in[4];
    const float* attn_b = (const float*)d_in[5];
    const float* comb_W = (const float*)d_in[6];
    const float* comb_b = (const float*)d_in[7];
    const float* w_ih_f = (const float*)d_in[8];
    const float* w_hh_f = (const float*)d_in[9];
    const float* b_ih_f = (const float*)d_in[10];
    const float* b_hh_f = (const float*)d_in[11];
    const float* w_ih_b = (const float*)d_in[12];
    const float* w_hh_b = (const float*)d_in[13];
    const float* b_ih_b = (const float*)d_in[14];
    const float* b_hh_b = (const float*)d_in[15];
    const float* w_ih_g = (const float*)d_in[16];
    const float* w_hh_g = (const float*)d_in[17];
    const float* b_ih_g = (const float*)d_in[18];
    const float* b_hh_g = (const float*)d_in[19];
    const float* out_W  = (const float*)d_in[20];
    const float* out_b  = (const float*)d_in[21];
    float* out = (float*)d_out;
    float* ws  = (float*)d_ws;

    void* args[] = {
        (void*)&token, (void*)&hidden, (void*)&enc, (void*)&emb,
        (void*)&attn_W, (void*)&attn_b, (void*)&comb_W, (void*)&comb_b,
        (void*)&w_ih_f, (void*)&w_hh_f, (void*)&b_ih_f, (void*)&b_hh_f,
        (void*)&w_ih_b, (void*)&w_hh_b, (void*)&b_ih_b, (void*)&b_hh_b,
        (void*)&w_ih_g, (void*)&w_hh_g, (void*)&b_ih_g, (void*)&b_hh_g,
        (void*)&out_W, (void*)&out_b, (void*)&out, (void*)&ws,
    };
    hipLaunchCooperativeKernel((const void*)fused_decoder,
                               dim3(NBLK), dim3(256), args, 0, stream);
}

// Round 4
// 177.790 us; speedup vs baseline: 2.7949x; 2.1550x over previous
//
#include <hip/hip_runtime.h>
#include <math.h>

#define H 256
#define L 50
#define V 50257
#define LOGIT_BLKS 786   // 786 blk * 4 waves * 16 rows = 50304 >= V

__device__ __forceinline__ float dot4(float4 a, float4 b) {
    return a.x * b.x + a.y * b.y + a.z * b.z + a.w * b.w;
}

__device__ __forceinline__ float wave_reduce_sum(float v) {
#pragma unroll
    for (int m = 32; m >= 1; m >>= 1) v += __shfl_xor(v, m, 64);
    return v;
}

__device__ __forceinline__ float wave_reduce_max(float v) {
#pragma unroll
    for (int m = 32; m >= 1; m >>= 1) v = fmaxf(v, __shfl_xor(v, m, 64));
    return v;
}

__device__ __forceinline__ float sigmoidf(float x) { return 1.0f / (1.0f + __expf(-x)); }

// online-softmax helpers (guarded against empty (-inf,0) states)
__device__ __forceinline__ void ms_push(float& m, float& s, float x) {
    float mn = fmaxf(m, x);
    s = s * __expf(m - mn) + __expf(x - mn);
    m = mn;
}
__device__ __forceinline__ void ms_merge(float& m, float& s, float om, float os) {
    float M = fmaxf(m, om);
    float a = (m == -INFINITY) ? 0.f : s * __expf(m - M);
    float c = (om == -INFINITY) ? 0.f : os * __expf(om - M);
    m = M; s = a + c;
}

// One GRU output element j computed by one wave.
__device__ __forceinline__ void gru_wave(
    int j, int lane, float4 xv, float4 hv, float hj,
    const float* __restrict__ w_ih, const float* __restrict__ w_hh,
    const float* __restrict__ b_ih, const float* __restrict__ b_hh,
    float* __restrict__ outp)
{
    float gi[3], gh[3];
#pragma unroll
    for (int k = 0; k < 3; ++k) {
        int row = k * H + j;
        const float4* wi4 = (const float4*)(w_ih + (size_t)row * H);
        const float4* wh4 = (const float4*)(w_hh + (size_t)row * H);
        gi[k] = wave_reduce_sum(dot4(wi4[lane], xv)) + b_ih[row];
        gh[k] = wave_reduce_sum(dot4(wh4[lane], hv)) + b_hh[row];
    }
    if (lane == 0) {
        float r = sigmoidf(gi[0] + gh[0]);
        float z = sigmoidf(gi[1] + gh[1]);
        float n = tanhf(gi[2] + r * gh[2]);
        outp[j] = (1.f - z) * n + z * hj;
    }
}

// ---- K1: scores[l] = relu(attn_W[l,:] . [e|h0] + attn_b[l]), 13 blocks ----
__global__ __launch_bounds__(256) void k_scores(
    const int* __restrict__ token, const float* __restrict__ hidden,
    const float* __restrict__ emb, const float* __restrict__ attn_W,
    const float* __restrict__ attn_b, float* __restrict__ ws_scores)
{
    __shared__ float s_vec[2 * H];
    int t = threadIdx.x, wid = t >> 6, lane = t & 63;
    int tok = token[0];
    s_vec[t] = emb[(size_t)tok * H + t];
    s_vec[H + t] = hidden[t];
    __syncthreads();
    int row = blockIdx.x * 4 + wid;
    if (row < L) {
        float acc = 0.f;
#pragma unroll
        for (int c = 0; c < 8; ++c)
            acc += attn_W[row * 2 * H + c * 64 + lane] * s_vec[c * 64 + lane];
        acc = wave_reduce_sum(acc);
        if (lane == 0) ws_scores[row] = fmaxf(acc + attn_b[row], 0.f);
    }
}

// ---- K2: softmax(scores) -> aw; applied = aw@enc; x = relu(comb_W@[e|applied]+b)
// 64 blocks; softmax+applied replicated per block (tiny, L2-hot). -------------
__global__ __launch_bounds__(256) void k_comb(
    const int* __restrict__ token, const float* __restrict__ emb,
    const float* __restrict__ enc, const float* __restrict__ comb_W,
    const float* __restrict__ comb_b, const float* __restrict__ ws_scores,
    float* __restrict__ ws_x, float* __restrict__ out_aw)
{
    __shared__ __align__(16) float s_cat[2 * H];
    __shared__ float s_aw[64];
    int t = threadIdx.x, wid = t >> 6, lane = t & 63;
    int tok = token[0];
    s_cat[t] = emb[(size_t)tok * H + t];      // e
    if (t < 64) {  // softmax over 50 in wave 0
        float v = (t < L) ? ws_scores[t] : -INFINITY;
        float mx = wave_reduce_max(v);
        float e = (t < L) ? __expf(v - mx) : 0.f;
        float ssum = wave_reduce_sum(e);
        if (t < L) {
            float aw = e / ssum;
            s_aw[t] = aw;
            if (blockIdx.x == 0) out_aw[t] = aw;   // third output
        }
    }
    __syncthreads();
    float app = 0.f;
    for (int l = 0; l < L; ++l) app += s_aw[l] * enc[l * H + t];
    s_cat[H + t] = app;
    __syncthreads();
    int row = blockIdx.x * 4 + wid;
    const float4* c4 = (const float4*)s_cat;
    const float4* W4 = (const float4*)(comb_W + (size_t)row * 2 * H);
    float acc = dot4(W4[lane], c4[lane]) + dot4(W4[lane + 64], c4[lane + 64]);
    acc = wave_reduce_sum(acc);
    if (lane == 0) ws_x[row] = fmaxf(acc + comb_b[row], 0.f);
}

// ---- K3: bidirectional GRU (hf, hb), 128 blocks, wave per (dir, j) ----------
__global__ __launch_bounds__(256) void k_gru_fb(
    const float* __restrict__ ws_x, const float* __restrict__ hidden,
    const float* __restrict__ w_ih_f, const float* __restrict__ w_hh_f,
    const float* __restrict__ b_ih_f, const float* __restrict__ b_hh_f,
    const float* __restrict__ w_ih_b, const float* __restrict__ w_hh_b,
    const float* __restrict__ b_ih_b, const float* __restrict__ b_hh_b,
    float* __restrict__ ws_hf, float* __restrict__ ws_hb)
{
    int t = threadIdx.x, wid = t >> 6, lane = t & 63;
    int g = blockIdx.x * 4 + wid;
    int dir = g >> 8, j = g & 255;
    gru_wave(j, lane, ((const float4*)ws_x)[lane], ((const float4*)hidden)[lane],
             hidden[j],
             dir ? w_ih_b : w_ih_f, dir ? w_hh_b : w_hh_f,
             dir ? b_ih_b : b_ih_f, dir ? b_hh_b : b_hh_f,
             dir ? ws_hb : ws_hf);
}

// ---- K4/K5: generic GRU cell, 64 blocks; hb!=null -> state = mean(ha,hb) ----
__global__ __launch_bounds__(256) void k_gru(
    const float* __restrict__ xvec, const float* __restrict__ ha,
    const float* __restrict__ hb,
    const float* __restrict__ w_ih, const float* __restrict__ w_hh,
    const float* __restrict__ b_ih, const float* __restrict__ b_hh,
    float* __restrict__ outp)
{
    int t = threadIdx.x, wid = t >> 6, lane = t & 63;
    int j = blockIdx.x * 4 + wid;
    float4 xv = ((const float4*)xvec)[lane];
    float4 hv = ((const float4*)ha)[lane];
    float hj;
    if (hb) {
        float4 bv = ((const float4*)hb)[lane];
        hv = make_float4(0.5f * (hv.x + bv.x), 0.5f * (hv.y + bv.y),
                         0.5f * (hv.z + bv.z), 0.5f * (hv.w + bv.w));
        hj = 0.5f * (ha[j] + hb[j]);
    } else {
        hj = ha[j];
    }
    gru_wave(j, lane, xv, hv, hj, w_ih, w_hh, b_ih, b_hh, outp);
}

// ---- K6: logits + per-block online-softmax partials. 786 blocks ------------
// Wave handles 16 consecutive rows, 2 in flight (12 waves/CU * 2KB in flight
// covers the BW*latency product for ~6 TB/s).
__global__ __launch_bounds__(256) void k_logits(
    const float* __restrict__ out_W, const float* __restrict__ out_b,
    const float* __restrict__ h1, float* __restrict__ logits,
    float* __restrict__ part_m, float* __restrict__ part_s)
{
    __shared__ float s_m4[4], s_s4[4];
    int t = threadIdx.x, wid = t >> 6, lane = t & 63;
    float4 hv = ((const float4*)h1)[lane];
    int base = (blockIdx.x * 4 + wid) * 16;
    float m = -INFINITY, s = 0.f;
#pragma unroll 1
    for (int k = 0; k < 16; k += 2) {
        int v = base + k;
        if (v >= V) break;
        const float4* W0 = (const float4*)(out_W + (size_t)v * H);
        float4 a0 = W0[lane];
        bool has2 = (v + 1 < V);
        float4 a1 = has2 ? ((const float4*)(out_W + (size_t)(v + 1) * H))[lane]
                         : make_float4(0.f, 0.f, 0.f, 0.f);
        float x0 = wave_reduce_sum(dot4(a0, hv)) + out_b[v];
        float x1 = wave_reduce_sum(dot4(a1, hv));
        if (lane == 0) logits[v] = x0;
        ms_push(m, s, x0);
        if (has2) {
            x1 += out_b[v + 1];
            if (lane == 0) logits[v + 1] = x1;
            ms_push(m, s, x1);
        }
    }
    if (lane == 0) { s_m4[wid] = m; s_s4[wid] = s; }
    __syncthreads();
    if (t == 0) {
        float M = s_m4[0], S = s_s4[0];
#pragma unroll
        for (int q = 1; q < 4; ++q) ms_merge(M, S, s_m4[q], s_s4[q]);
        part_m[blockIdx.x] = M; part_s[blockIdx.x] = S;
    }
}

// ---- K7: fold 786 partials -> lse (replicated per block); subtract ---------
__global__ __launch_bounds__(256) void k_final(
    const float* __restrict__ part_m, const float* __restrict__ part_s,
    float* __restrict__ logits)
{
    __shared__ float s_m4[4], s_s4[4];
    __shared__ float s_bcast;
    int t = threadIdx.x, wid = t >> 6, lane = t & 63;
    float m = -INFINITY, s = 0.f;
    for (int idx = t; idx < LOGIT_BLKS; idx += 256)
        ms_merge(m, s, part_m[idx], part_s[idx]);
#pragma unroll
    for (int d = 32; d >= 1; d >>= 1) {
        float om = __shfl_xor(m, d, 64);
        float os = __shfl_xor(s, d, 64);
        ms_merge(m, s, om, os);
    }
    if (lane == 0) { s_m4[wid] = m; s_s4[wid] = s; }
    __syncthreads();
    if (t == 0) {
        float M = s_m4[0], S = s_s4[0];
#pragma unroll
        for (int q = 1; q < 4; ++q) ms_merge(M, S, s_m4[q], s_s4[q]);
        s_bcast = M + logf(S);
    }
    __syncthreads();
    float lse = s_bcast;
    int i = blockIdx.x * 256 + t;
    if (i < V) logits[i] -= lse;
}

extern "C" void kernel_launch(void* const* d_in, const int* in_sizes, int n_in,
                              void* d_out, int out_size, void* d_ws, size_t ws_size,
                              hipStream_t stream)
{
    const int*   token  = (const int*)d_in[0];
    const float* hidden = (const float*)d_in[1];
    const float* enc    = (const float*)d_in[2];
    const float* emb    = (const float*)d_in[3];
    const float* attn_W = (const float*)d_in[4];
    const float* attn_b = (const float*)d_in[5];
    const float* comb_W = (const float*)d_in[6];
    const float* comb_b = (const float*)d_in[7];
    const float* w_ih_f = (const float*)d_in[8];
    const float* w_hh_f = (const float*)d_in[9];
    const float* b_ih_f = (const float*)d_in[10];
    const float* b_hh_f = (const float*)d_in[11];
    const float* w_ih_b = (const float*)d_in[12];
    const float* w_hh_b = (const float*)d_in[13];
    const float* b_ih_b = (const float*)d_in[14];
    const float* b_hh_b = (const float*)d_in[15];
    const float* w_ih_g = (const float*)d_in[16];
    const float* w_hh_g = (const float*)d_in[17];
    const float* b_ih_g = (const float*)d_in[18];
    const float* b_hh_g = (const float*)d_in[19];
    const float* out_W  = (const float*)d_in[20];
    const float* out_b  = (const float*)d_in[21];

    float* out = (float*)d_out;   // [V logp | H h2 | L aw]
    float* ws  = (float*)d_ws;
    float* ws_scores = ws;            // 64
    float* ws_x      = ws + 64;       // 256
    float* ws_hf     = ws + 320;      // 256
    float* ws_hb     = ws + 576;      // 256
    float* ws_h1     = ws + 832;      // 256
    float* part_m    = ws + 1088;     // 786
    float* part_s    = ws + 1888;     // 786

    k_scores<<<13, 256, 0, stream>>>(token, hidden, emb, attn_W, attn_b, ws_scores);
    k_comb<<<64, 256, 0, stream>>>(token, emb, enc, comb_W, comb_b, ws_scores,
                                   ws_x, out + V + H);
    k_gru_fb<<<128, 256, 0, stream>>>(ws_x, hidden,
                                      w_ih_f, w_hh_f, b_ih_f, b_hh_f,
                                      w_ih_b, w_hh_b, b_ih_b, b_hh_b,
                                      ws_hf, ws_hb);
    k_gru<<<64, 256, 0, stream>>>(ws_hf, ws_hf, ws_hb,
                                  w_ih_g, w_hh_g, b_ih_g, b_hh_g, ws_h1);
    k_gru<<<64, 256, 0, stream>>>(ws_hb, ws_h1, nullptr,
                                  w_ih_g, w_hh_g, b_ih_g, b_hh_g, out + V);
    k_logits<<<LOGIT_BLKS, 256, 0, stream>>>(out_W, out_b, ws_h1, out,
                                             part_m, part_s);
    k_final<<<197, 256, 0, stream>>>(part_m, part_s, out);
}